// Round 5
// baseline (547.543 us; speedup 1.0000x reference)
//
#include <hip/hip_runtime.h>
#include <hip/hip_bf16.h>
#include <stdint.h>

#define NTOK  4096
#define TOPK  2
#define NEXP  8
#define HID   1024
#define INTER 2048
#define NPAIR (NTOK*TOPK)
#define MAXTILE 72   // sum_e ceil(cnt_e/128) <= 71 since sum cnt = 8192

typedef __attribute__((ext_vector_type(8))) short short8;
typedef __attribute__((ext_vector_type(4))) float floatx4;

#define AS1(p) ((const __attribute__((address_space(1))) void*)(p))
#define AS3(p) ((__attribute__((address_space(3))) void*)(p))

// ---------------- ws layout (bytes) ----------------
// ctrl @0: counts(8)@0, offsets@64, fill@128, flags(6)@192, ntiles@240,
//          tile_e(72)@256, tile_m(72)@1024
#define O_PERMTOK 4096ull
#define O_PERMW   (O_PERMTOK + (size_t)NPAIR*4)             // float[NPAIR]
#define O_X       (1ull<<20)                                 // bf16 [NPAIR][HID]      16 MB
#define O_WGU     (O_X   + (size_t)NPAIR*HID*2)              // bf16 [E][2*INTER][HID] 64 MB (g/u 16-row interleave)
#define O_WD      (O_WGU + (size_t)NEXP*2*INTER*HID*2)       // bf16 [E][HID][INTER]   32 MB
#define O_HB      (O_WD  + (size_t)NEXP*HID*INTER*2)         // bf16 [NPAIR][INTER]    32 MB
#define WS_NEEDED (O_HB  + (size_t)NPAIR*INTER*2)

static __device__ __forceinline__ unsigned short f32_to_bf16_rne(float f) {
    union { float f; uint32_t u; } v; v.f = f;
    uint32_t b = v.u + 0x7fffu + ((v.u >> 16) & 1u);
    return (unsigned short)(b >> 16);
}
static __device__ __forceinline__ float bf16_to_f32(unsigned short u) {
    union { uint32_t i; float f; } cv; cv.i = ((uint32_t)u) << 16;
    return cv.f;
}

// ---------------- dtype probes ----------------
__global__ void k_probe(const void* __restrict__ tok, const void* __restrict__ ew,
                        const void* __restrict__ gw,  const void* __restrict__ uw,
                        const void* __restrict__ dw,  const void* __restrict__ eidx,
                        int* __restrict__ flags) {
    int lane = threadIdx.x;  // 64
    const void* ptrs[5] = { tok, ew, gw, uw, dw };
    for (int t = 0; t < 5; ++t) {
        const unsigned short* p = (const unsigned short*)ptrs[t];
        float v = bf16_to_f32(p[lane * 2]);
        unsigned long long m = __ballot(!(fabsf(v) < 1000.0f));
        if (lane == 0) flags[t] = (m != 0ull) ? 1 : 0;
    }
    const int* ix = (const int*)eidx;
    unsigned long long mi = __ballot(ix[lane * 2 + 1] != 0);
    if (lane == 0) flags[5] = (mi == 0ull) ? 1 : 0;
}

// ---------------- routing ----------------
__global__ void k_route_count(const int* __restrict__ idx, int* __restrict__ counts,
                              const int* __restrict__ flags) {
    int i64 = flags[5];
    int p = blockIdx.x * 256 + threadIdx.x;
    if (p < NPAIR) atomicAdd(&counts[idx[p << i64]], 1);
}

// prefix scan + compact M-tile table (BM=128)
__global__ void k_route_scan(const int* __restrict__ counts, int* __restrict__ offsets,
                             int* __restrict__ fill, int* __restrict__ ntiles,
                             int* __restrict__ tile_e, int* __restrict__ tile_m) {
    if (threadIdx.x == 0) {
        int acc = 0, nt = 0;
        for (int e = 0; e < NEXP; ++e) {
            offsets[e] = acc;
            for (int m = 0; m < counts[e]; m += 128) {
                tile_e[nt] = e; tile_m[nt] = m; ++nt;
            }
            acc += counts[e]; fill[e] = 0;
        }
        *ntiles = nt;
    }
}

__global__ void k_route_fill(const int* __restrict__ idx, const void* __restrict__ ew,
                             const int* __restrict__ offsets, int* __restrict__ fill,
                             int* __restrict__ perm_tok, float* __restrict__ perm_w,
                             const int* __restrict__ flags) {
    int ewf = flags[1], i64 = flags[5];
    int p = blockIdx.x * 256 + threadIdx.x;
    if (p < NPAIR) {
        int e = idx[p << i64];
        int pos = offsets[e] + atomicAdd(&fill[e], 1);
        perm_tok[pos] = p >> 1;
        perm_w[pos]   = ewf ? ((const float*)ew)[p]
                            : bf16_to_f32(((const unsigned short*)ew)[p]);
    }
}

// gather packed token rows -> bf16 X
__global__ void k_gather(const void* __restrict__ tokens, const int* __restrict__ perm_tok,
                         unsigned short* __restrict__ X, const int* __restrict__ flags) {
    int f = flags[0];
    int pos = blockIdx.x;
    int tok = perm_tok[pos];
    ushort4* d = (ushort4*)(X + (size_t)pos * HID);
    if (f) {
        float4 v = *(const float4*)((const float*)tokens + (size_t)tok * HID + threadIdx.x * 4);
        ushort4 o;
        o.x = f32_to_bf16_rne(v.x); o.y = f32_to_bf16_rne(v.y);
        o.z = f32_to_bf16_rne(v.z); o.w = f32_to_bf16_rne(v.w);
        d[threadIdx.x] = o;
    } else {
        d[threadIdx.x] = ((const ushort4*)((const unsigned short*)tokens + (size_t)tok * HID))[threadIdx.x];
    }
}

// unified weight transpose: z in [0,24): typ = z>>3 (0 gate, 1 up, 2 down), e = z&7.
// gate/up: src [HID][INTER] -> Wgu rows 32*(c>>4)+(c&15) (+16 for up), stride HID.
// down:    src [INTER][HID] -> Wd rows c, stride INTER.
__global__ void k_transpose_all(const void* __restrict__ gw, const void* __restrict__ uw,
                                const void* __restrict__ dwp,
                                unsigned short* __restrict__ Wgu, unsigned short* __restrict__ Wd,
                                const int* __restrict__ flags) {
    __shared__ unsigned short tile[32][34];
    const int z = blockIdx.y;
    const int typ = z >> 3, e = z & 7;
    const int R = (typ == 2) ? INTER : HID;
    const int C = (typ == 2) ? HID : INTER;
    const void* src = (typ == 0) ? gw : (typ == 1) ? uw : dwp;
    const int isf32 = flags[2 + typ];
    const size_t eoff = (size_t)e * HID * INTER;
    const float* sf = (const float*)src + eoff;
    const unsigned short* sh = (const unsigned short*)src + eoff;
    unsigned short* dst = (typ == 2) ? (Wd + eoff) : (Wgu + (size_t)e * 2 * INTER * HID);

    const int nbc = C / 32;
    const int bx = blockIdx.x;                 // 2048 = (C/32)*(R/32)
    const int c0 = (bx % nbc) * 32, r0 = (bx / nbc) * 32;
    const int tx = threadIdx.x, ty = threadIdx.y;  // (32,8)
#pragma unroll
    for (int i = 0; i < 32; i += 8) {
        size_t si = (size_t)(r0 + ty + i) * C + (c0 + tx);
        tile[ty + i][tx] = isf32 ? f32_to_bf16_rne(sf[si]) : sh[si];
    }
    __syncthreads();
#pragma unroll
    for (int i = 0; i < 32; i += 8) {
        int c = c0 + ty + i;
        int drow = (typ == 2) ? c : (((c >> 4) << 5) + (c & 15) + ((typ == 1) ? 16 : 0));
        dst[(size_t)drow * R + (r0 + tx)] = tile[tx][ty + i];
    }
}

// ---------------- MFMA core: 128x128 tile, BK=64, double-buffered 2-phase ----------------
// LDS per matrix: [2][128 rows x 64 hw], XOR-swizzled (chunk ^= row&7); staged via
// global_load_lds with pre-swizzled global source (rule #21). One barrier per K-step:
// stage(next half) FIRST, then ds_read+MFMA(current half), then __syncthreads()
// (compiler-inserted vmcnt(0) drains AFTER compute -> load latency hidden). T3 minimum-2-phase.
__device__ __forceinline__ void stg16(const char* g, const unsigned short* ldsb) {
    __builtin_amdgcn_global_load_lds(AS1(g), AS3(ldsb), 16, 0, 0);
}

template<int KHW, int NKT>
__device__ __forceinline__ void coreK(
    const unsigned short* __restrict__ Ab, int arowlim,
    const unsigned short* __restrict__ Bb,
    unsigned short* sA, unsigned short* sB,
    int tid, floatx4 (&acc)[4][4])
{
    const int wave = tid >> 6, lane = tid & 63;
    const int q = lane >> 4, l15 = lane & 15;
    const int wm = (wave >> 1) * 64, wn = (wave & 1) * 64;

    const int rl = lane >> 3;                 // 0..7: row within 8-row group
    const int sch = (lane & 7) ^ (rl & 7);    // pre-swizzled global chunk

    const char* gA[4]; const char* gB[4]; unsigned lb[4];
#pragma unroll
    for (int t = 0; t < 4; ++t) {
        int r = wave * 32 + t * 8 + rl;
        int ar = min(r, arowlim);
        gA[t] = (const char*)(Ab + (size_t)ar * KHW) + sch * 16;
        gB[t] = (const char*)(Bb + (size_t)r  * KHW) + sch * 16;
        lb[t] = (unsigned)((wave * 32 + t * 8) * 64);   // hw, wave-uniform
    }

    const unsigned c0b = (unsigned)((q ^ (l15 & 7)) * 16);
    const char* cA = (const char*)sA;
    const char* cB = (const char*)sB;

    // prologue: stage K-tile 0 into half 0
#pragma unroll
    for (int t = 0; t < 4; ++t) stg16(gA[t], sA + lb[t]);
#pragma unroll
    for (int t = 0; t < 4; ++t) stg16(gB[t], sB + lb[t]);
    __syncthreads();

#pragma unroll 1
    for (int kt = 0; kt < NKT; ++kt) {
        const int cur = kt & 1;
        const unsigned curb = (unsigned)cur * 16384u;       // bytes
        if (kt + 1 < NKT) {
            const int kb = (kt + 1) * 128;                  // bytes along K
            const unsigned nxtb = (unsigned)(cur ^ 1) * 8192u;  // hw
#pragma unroll
            for (int t = 0; t < 4; ++t) stg16(gA[t] + kb, sA + nxtb + lb[t]);
#pragma unroll
            for (int t = 0; t < 4; ++t) stg16(gB[t] + kb, sB + nxtb + lb[t]);
        }
        short8 af[4][2], bfr[4][2];
#pragma unroll
        for (int i = 0; i < 4; ++i)
#pragma unroll
            for (int ks = 0; ks < 2; ++ks)
                af[i][ks] = *(const short8*)(cA + curb + (wm + i * 16 + l15) * 128 + (c0b ^ (ks << 6)));
#pragma unroll
        for (int j = 0; j < 4; ++j)
#pragma unroll
            for (int ks = 0; ks < 2; ++ks)
                bfr[j][ks] = *(const short8*)(cB + curb + (wn + j * 16 + l15) * 128 + (c0b ^ (ks << 6)));
#pragma unroll
        for (int i = 0; i < 4; ++i)
#pragma unroll
            for (int j = 0; j < 4; ++j) {
                acc[i][j] = __builtin_amdgcn_mfma_f32_16x16x32_bf16(af[i][0], bfr[j][0], acc[i][j], 0, 0, 0);
                acc[i][j] = __builtin_amdgcn_mfma_f32_16x16x32_bf16(af[i][1], bfr[j][1], acc[i][j], 0, 0, 0);
            }
        __syncthreads();
    }
}

// ---------------- k_gu: Hbuf = silu(X*Wg^T) * (X*Wu^T) via interleaved Wgu ----------------
// Wgu rows n: (n&31)<16 -> gate col (n>>5)*16+(n&15); else up col same. Block computes
// GU rows [nt0, nt0+128): j even = gate frag, j odd = matching up frag.
__global__ __launch_bounds__(256, 2) void k_gu(
    const unsigned short* __restrict__ X, const unsigned short* __restrict__ Wgu,
    unsigned short* __restrict__ Hbuf,
    const int* __restrict__ counts, const int* __restrict__ offsets,
    const int* __restrict__ tile_e, const int* __restrict__ tile_m,
    const int* __restrict__ ntiles)
{
    const int t = blockIdx.x;
    if (t >= *ntiles) return;
    const int e = tile_e[t], m0 = tile_m[t];
    const int cnt = counts[e], off = offsets[e];
    const int nt0 = blockIdx.y * 128;   // GU row-block in [0, 4096)

    __shared__ __align__(16) unsigned short sA[2 * 128 * 64];
    __shared__ __align__(16) unsigned short sB[2 * 128 * 64];

    const int tid = threadIdx.x;
    const int wave = tid >> 6, lane = tid & 63;
    const int wm = (wave >> 1) * 64, wn = (wave & 1) * 64;
    const int q = lane >> 4, l15 = lane & 15;

    floatx4 acc[4][4];
#pragma unroll
    for (int i = 0; i < 4; ++i)
#pragma unroll
        for (int j = 0; j < 4; ++j)
#pragma unroll
            for (int r = 0; r < 4; ++r) acc[i][j][r] = 0.f;

    coreK<HID, HID / 64>(X + (size_t)(off + m0) * HID, NPAIR - 1 - (off + m0),
                         Wgu + (size_t)e * 2 * INTER * HID + (size_t)nt0 * HID,
                         sA, sB, tid, acc);

#pragma unroll
    for (int i = 0; i < 4; ++i)
#pragma unroll
        for (int r = 0; r < 4; ++r) {
            int row = m0 + wm + i * 16 + q * 4 + r;
            if (row < cnt) {
                unsigned short* hrow = Hbuf + (size_t)(off + row) * INTER;
#pragma unroll
                for (int jp = 0; jp < 2; ++jp) {
                    int j = jp * 2;
                    float g = acc[i][j][r], u = acc[i][j + 1][r];
                    float s = g / (1.0f + __expf(-g));
                    int icol = (nt0 + wn) / 2 + jp * 16 + l15;
                    hrow[icol] = f32_to_bf16_rne(s * u);
                }
            }
        }
}

// ---------------- k_d: out[token] += w * (Hbuf * Wd^T), split-K=2 ----------------
__global__ __launch_bounds__(256, 2) void k_d(
    const unsigned short* __restrict__ Hbuf, const unsigned short* __restrict__ Wd,
    float* __restrict__ outf,
    const int* __restrict__ counts, const int* __restrict__ offsets,
    const int* __restrict__ perm_tok, const float* __restrict__ perm_w,
    const int* __restrict__ tile_e, const int* __restrict__ tile_m,
    const int* __restrict__ ntiles)
{
    const int t = blockIdx.x;
    if (t >= *ntiles) return;
    const int e = tile_e[t], m0 = tile_m[t];
    const int cnt = counts[e], off = offsets[e];
    const int nt0 = blockIdx.y * 128;   // [0, 1024)
    const int z = blockIdx.z;           // K-half: hw offset z*1024

    __shared__ __align__(16) unsigned short sA[2 * 128 * 64];
    __shared__ __align__(16) unsigned short sB[2 * 128 * 64];

    const int tid = threadIdx.x;
    const int wave = tid >> 6, lane = tid & 63;
    const int wm = (wave >> 1) * 64, wn = (wave & 1) * 64;
    const int q = lane >> 4, l15 = lane & 15;

    floatx4 acc[4][4];
#pragma unroll
    for (int i = 0; i < 4; ++i)
#pragma unroll
        for (int j = 0; j < 4; ++j)
#pragma unroll
            for (int r = 0; r < 4; ++r) acc[i][j][r] = 0.f;

    coreK<INTER, 16>(Hbuf + (size_t)(off + m0) * INTER + z * 1024, NPAIR - 1 - (off + m0),
                     Wd + (size_t)e * HID * INTER + (size_t)nt0 * INTER + z * 1024,
                     sA, sB, tid, acc);

#pragma unroll
    for (int i = 0; i < 4; ++i)
#pragma unroll
        for (int r = 0; r < 4; ++r) {
            int row = m0 + wm + i * 16 + q * 4 + r;
            if (row < cnt) {
                int gpos = off + row;
                int tok = perm_tok[gpos];
                float w = perm_w[gpos];
                float* orow = outf + (size_t)tok * HID + nt0;
#pragma unroll
                for (int j = 0; j < 4; ++j) {
#ifdef __HIP_PLATFORM_AMD__
                    unsafeAtomicAdd(&orow[wn + j * 16 + l15], w * acc[i][j][r]);
#else
                    atomicAdd(&orow[wn + j * 16 + l15], w * acc[i][j][r]);
#endif
                }
            }
        }
}

extern "C" void kernel_launch(void* const* d_in, const int* in_sizes, int n_in,
                              void* d_out, int out_size, void* d_ws, size_t ws_size,
                              hipStream_t stream) {
    const void* tokens = d_in[0];
    const void* eidx   = d_in[1];
    const void* ew     = d_in[2];
    const void* gw     = d_in[3];
    const void* uw     = d_in[4];
    const void* dwp    = d_in[5];
    float* out = (float*)d_out;
    char* ws = (char*)d_ws;

    if (ws_size < WS_NEEDED) {
        hipMemsetAsync(d_out, 0, (size_t)out_size * 4, stream);
        return;
    }

    int*   counts   = (int*)(ws + 0);
    int*   offsets  = (int*)(ws + 64);
    int*   fill     = (int*)(ws + 128);
    int*   flags    = (int*)(ws + 192);
    int*   ntiles   = (int*)(ws + 240);
    int*   tile_e   = (int*)(ws + 256);
    int*   tile_m   = (int*)(ws + 1024);
    int*   perm_tok = (int*)(ws + O_PERMTOK);
    float* perm_w   = (float*)(ws + O_PERMW);
    unsigned short* X   = (unsigned short*)(ws + O_X);
    unsigned short* Wgu = (unsigned short*)(ws + O_WGU);
    unsigned short* Wd  = (unsigned short*)(ws + O_WD);
    unsigned short* Hb  = (unsigned short*)(ws + O_HB);

    hipMemsetAsync(counts, 0, 256, stream);
    hipMemsetAsync(out, 0, (size_t)out_size * 4, stream);

    k_probe<<<1, 64, 0, stream>>>(tokens, ew, gw, uw, dwp, eidx, flags);
    k_route_count<<<NPAIR / 256, 256, 0, stream>>>((const int*)eidx, counts, flags);
    k_route_scan<<<1, 64, 0, stream>>>(counts, offsets, fill, ntiles, tile_e, tile_m);
    k_route_fill<<<NPAIR / 256, 256, 0, stream>>>((const int*)eidx, ew, offsets, fill,
                                                  perm_tok, perm_w, flags);
    k_gather<<<NPAIR, 256, 0, stream>>>(tokens, perm_tok, X, flags);

    k_transpose_all<<<dim3(2048, 24), dim3(32, 8), 0, stream>>>(gw, uw, dwp, Wgu, Wd, flags);

    k_gu<<<dim3(MAXTILE, 2 * INTER / 128), 256, 0, stream>>>(X, Wgu, Hb, counts, offsets,
                                                             tile_e, tile_m, ntiles);
    k_d<<<dim3(MAXTILE, HID / 128, 2), 256, 0, stream>>>(Hb, Wd, out, counts, offsets,
                                                         perm_tok, perm_w, tile_e, tile_m, ntiles);
}

// Round 9
// 517.711 us; speedup vs baseline: 1.0576x; 1.0576x over previous
//
#include <hip/hip_runtime.h>
#include <hip/hip_bf16.h>
#include <stdint.h>

#define NTOK  4096
#define TOPK  2
#define NEXP  8
#define HID   1024
#define INTER 2048
#define NPAIR (NTOK*TOPK)
#define MAXTILE 72   // sum_e ceil(cnt_e/128) <= 71 since sum cnt = 8192

typedef __attribute__((ext_vector_type(8))) short short8;
typedef __attribute__((ext_vector_type(4))) float floatx4;

#define AS1(p) ((const __attribute__((address_space(1))) void*)(p))
#define AS3(p) ((__attribute__((address_space(3))) void*)(p))

// ---------------- ws layout (bytes) ----------------
// ctrl @0: counts(8)@0, offsets@64, fill@128, flags(6)@192, ntiles@240,
//          tile_e(72)@256, tile_m(72)@1024
#define O_PERMTOK 4096ull
#define O_PERMW   (O_PERMTOK + (size_t)NPAIR*4)            // float[NPAIR]
#define O_X       (1ull<<20)                                // bf16 [NPAIR][HID]    16 MB
#define O_WG      (O_X  + (size_t)NPAIR*HID*2)              // bf16 [E][INTER][HID] 32 MB
#define O_WU      (O_WG + (size_t)NEXP*INTER*HID*2)         // bf16 [E][INTER][HID] 32 MB
#define O_WD      (O_WU + (size_t)NEXP*INTER*HID*2)         // bf16 [E][HID][INTER] 32 MB
#define O_HB      (O_WD + (size_t)NEXP*HID*INTER*2)         // bf16 [NPAIR][INTER]  32 MB
#define WS_NEEDED (O_HB + (size_t)NPAIR*INTER*2)

static __device__ __forceinline__ unsigned short f32_to_bf16_rne(float f) {
    union { float f; uint32_t u; } v; v.f = f;
    uint32_t b = v.u + 0x7fffu + ((v.u >> 16) & 1u);
    return (unsigned short)(b >> 16);
}
static __device__ __forceinline__ float bf16_to_f32(unsigned short u) {
    union { uint32_t i; float f; } cv; cv.i = ((uint32_t)u) << 16;
    return cv.f;
}

// ---------------- dtype probes ----------------
__global__ void k_probe(const void* __restrict__ tok, const void* __restrict__ ew,
                        const void* __restrict__ gw,  const void* __restrict__ uw,
                        const void* __restrict__ dw,  const void* __restrict__ eidx,
                        int* __restrict__ flags) {
    int lane = threadIdx.x;  // 64
    const void* ptrs[5] = { tok, ew, gw, uw, dw };
    for (int t = 0; t < 5; ++t) {
        const unsigned short* p = (const unsigned short*)ptrs[t];
        float v = bf16_to_f32(p[lane * 2]);
        unsigned long long m = __ballot(!(fabsf(v) < 1000.0f));
        if (lane == 0) flags[t] = (m != 0ull) ? 1 : 0;
    }
    const int* ix = (const int*)eidx;
    unsigned long long mi = __ballot(ix[lane * 2 + 1] != 0);
    if (lane == 0) flags[5] = (mi == 0ull) ? 1 : 0;
}

// ---------------- routing ----------------
__global__ void k_route_count(const int* __restrict__ idx, int* __restrict__ counts,
                              const int* __restrict__ flags) {
    int i64 = flags[5];
    int p = blockIdx.x * 256 + threadIdx.x;
    if (p < NPAIR) atomicAdd(&counts[idx[p << i64]], 1);
}

// prefix scan + compact M-tile table (BM=128)
__global__ void k_route_scan(const int* __restrict__ counts, int* __restrict__ offsets,
                             int* __restrict__ fill, int* __restrict__ ntiles,
                             int* __restrict__ tile_e, int* __restrict__ tile_m) {
    if (threadIdx.x == 0) {
        int acc = 0, nt = 0;
        for (int e = 0; e < NEXP; ++e) {
            offsets[e] = acc;
            for (int m = 0; m < counts[e]; m += 128) {
                tile_e[nt] = e; tile_m[nt] = m; ++nt;
            }
            acc += counts[e]; fill[e] = 0;
        }
        *ntiles = nt;
    }
}

__global__ void k_route_fill(const int* __restrict__ idx, const void* __restrict__ ew,
                             const int* __restrict__ offsets, int* __restrict__ fill,
                             int* __restrict__ perm_tok, float* __restrict__ perm_w,
                             const int* __restrict__ flags) {
    int ewf = flags[1], i64 = flags[5];
    int p = blockIdx.x * 256 + threadIdx.x;
    if (p < NPAIR) {
        int e = idx[p << i64];
        int pos = offsets[e] + atomicAdd(&fill[e], 1);
        perm_tok[pos] = p >> 1;
        perm_w[pos]   = ewf ? ((const float*)ew)[p]
                            : bf16_to_f32(((const unsigned short*)ew)[p]);
    }
}

// gather packed token rows -> bf16 X
__global__ void k_gather(const void* __restrict__ tokens, const int* __restrict__ perm_tok,
                         unsigned short* __restrict__ X, const int* __restrict__ flags) {
    int f = flags[0];
    int pos = blockIdx.x;
    int tok = perm_tok[pos];
    ushort4* d = (ushort4*)(X + (size_t)pos * HID);
    if (f) {
        float4 v = *(const float4*)((const float*)tokens + (size_t)tok * HID + threadIdx.x * 4);
        ushort4 o;
        o.x = f32_to_bf16_rne(v.x); o.y = f32_to_bf16_rne(v.y);
        o.z = f32_to_bf16_rne(v.z); o.w = f32_to_bf16_rne(v.w);
        d[threadIdx.x] = o;
    } else {
        d[threadIdx.x] = ((const ushort4*)((const unsigned short*)tokens + (size_t)tok * HID))[threadIdx.x];
    }
}

// ---------------- vectorized transpose [R][C] -> bf16 [C][R] per expert ----------------
// 64x64 tiles, (32,8) threads, each thread 8 rows x 2 cols.
// Reads float2/ushort2 (256B / 128B per 32 lanes); writes ushort2 (128B per 32 lanes).
// LDS [64][66]: write side conflict-free (banks (rl*33+tx)%32 distinct per row).
__global__ void k_transpose64(const void* __restrict__ src,
                              unsigned short* __restrict__ dst, int R, int C,
                              const int* __restrict__ flags, int flagIdx) {
    __shared__ unsigned short tile[64][66];
    const int isf32 = flags[flagIdx];
    const size_t eoff = (size_t)blockIdx.z * R * C;
    const float* sf = (const float*)src + eoff;
    const unsigned short* sh = (const unsigned short*)src + eoff;
    dst += eoff;
    const int c0 = blockIdx.x * 64, r0 = blockIdx.y * 64;
    const int tx = threadIdx.x, ty = threadIdx.y;  // (32,8)

    if (isf32) {
#pragma unroll
        for (int k = 0; k < 8; ++k) {
            int rl = ty + k * 8;
            float2 v = *(const float2*)(sf + (size_t)(r0 + rl) * C + c0 + tx * 2);
            tile[rl][tx * 2]     = f32_to_bf16_rne(v.x);
            tile[rl][tx * 2 + 1] = f32_to_bf16_rne(v.y);
        }
    } else {
#pragma unroll
        for (int k = 0; k < 8; ++k) {
            int rl = ty + k * 8;
            ushort2 v = *(const ushort2*)(sh + (size_t)(r0 + rl) * C + c0 + tx * 2);
            tile[rl][tx * 2] = v.x; tile[rl][tx * 2 + 1] = v.y;
        }
    }
    __syncthreads();
#pragma unroll
    for (int k = 0; k < 8; ++k) {
        int cl = ty + k * 8;
        ushort2 o;
        o.x = tile[tx * 2][cl];
        o.y = tile[tx * 2 + 1][cl];
        *(ushort2*)(dst + (size_t)(c0 + cl) * R + r0 + tx * 2) = o;
    }
}

// ---------------- MFMA core: 128x128 tile, BK=64, global_load_lds, 2-barrier (R4-proven) ----------------
// LDS per matrix: 128 rows x 64 hw (128 B), XOR-swizzled: LDS[row][slot] holds
// global chunk slot^(row&7). Stage: lane writes slot lane&7 of row wave*32+t*8+(lane>>3),
// so its global chunk = (lane&7)^((lane>>3)&7). Read: slot (ks*4+q)^(l15&7).
__device__ __forceinline__ void stg16(const char* g, const unsigned short* ldsb) {
    __builtin_amdgcn_global_load_lds(AS1(g), AS3(ldsb), 16, 0, 0);
}

template<int KHW>
__device__ __forceinline__ void mfma_core(
    const unsigned short* __restrict__ Ab, int arowlim,
    const unsigned short* __restrict__ Bb,
    unsigned short* sA, unsigned short* sB,
    int tid, floatx4 (&acc)[4][4])
{
    const int wave = tid >> 6, lane = tid & 63;
    const int q = lane >> 4, l15 = lane & 15;
    const int wm = (wave >> 1) * 64, wn = (wave & 1) * 64;

    const int rl = lane >> 3;                 // 0..7: row within 8-row group
    const int sch = (lane & 7) ^ (rl & 7);    // pre-swizzled global chunk

    const char* gA[4]; const char* gB[4]; unsigned lb[4];
#pragma unroll
    for (int t = 0; t < 4; ++t) {
        int r = wave * 32 + t * 8 + rl;
        int ar = min(r, arowlim);
        gA[t] = (const char*)(Ab + (size_t)ar * KHW) + sch * 16;
        gB[t] = (const char*)(Bb + (size_t)r  * KHW) + sch * 16;
        lb[t] = (unsigned)((wave * 32 + t * 8) * 64);   // hw, wave-uniform
    }

    const unsigned c0b = (unsigned)((q ^ (l15 & 7)) * 16);
    const char* cA = (const char*)sA;
    const char* cB = (const char*)sB;

#pragma unroll 1
    for (int kk = 0; kk < KHW / 64; ++kk) {
        const int kb = kk * 128;
#pragma unroll
        for (int t = 0; t < 4; ++t) stg16(gA[t] + kb, sA + lb[t]);
#pragma unroll
        for (int t = 0; t < 4; ++t) stg16(gB[t] + kb, sB + lb[t]);
        __syncthreads();
        short8 af[4][2], bfr[4][2];
#pragma unroll
        for (int i = 0; i < 4; ++i)
#pragma unroll
            for (int ks = 0; ks < 2; ++ks)
                af[i][ks] = *(const short8*)(cA + (wm + i * 16 + l15) * 128 + (c0b ^ (ks << 6)));
#pragma unroll
        for (int j = 0; j < 4; ++j)
#pragma unroll
            for (int ks = 0; ks < 2; ++ks)
                bfr[j][ks] = *(const short8*)(cB + (wn + j * 16 + l15) * 128 + (c0b ^ (ks << 6)));
#pragma unroll
        for (int i = 0; i < 4; ++i)
#pragma unroll
            for (int j = 0; j < 4; ++j) {
                acc[i][j] = __builtin_amdgcn_mfma_f32_16x16x32_bf16(af[i][0], bfr[j][0], acc[i][j], 0, 0, 0);
                acc[i][j] = __builtin_amdgcn_mfma_f32_16x16x32_bf16(af[i][1], bfr[j][1], acc[i][j], 0, 0, 0);
            }
        __syncthreads();
    }
}

// fused dual-B core: one A staging feeds Wg and Wu products (64 MFMA / iter)
template<int KHW>
__device__ __forceinline__ void mfma_core2(
    const unsigned short* __restrict__ Ab, int arowlim,
    const unsigned short* __restrict__ Bg, const unsigned short* __restrict__ Bu,
    unsigned short* sA, unsigned short* sBg, unsigned short* sBu,
    int tid, floatx4 (&accg)[4][4], floatx4 (&accu)[4][4])
{
    const int wave = tid >> 6, lane = tid & 63;
    const int q = lane >> 4, l15 = lane & 15;
    const int wm = (wave >> 1) * 64, wn = (wave & 1) * 64;

    const int rl = lane >> 3;
    const int sch = (lane & 7) ^ (rl & 7);

    const char* gA[4]; const char* gG[4]; const char* gU[4]; unsigned lb[4];
#pragma unroll
    for (int t = 0; t < 4; ++t) {
        int r = wave * 32 + t * 8 + rl;
        int ar = min(r, arowlim);
        gA[t] = (const char*)(Ab + (size_t)ar * KHW) + sch * 16;
        gG[t] = (const char*)(Bg + (size_t)r  * KHW) + sch * 16;
        gU[t] = (const char*)(Bu + (size_t)r  * KHW) + sch * 16;
        lb[t] = (unsigned)((wave * 32 + t * 8) * 64);
    }

    const unsigned c0b = (unsigned)((q ^ (l15 & 7)) * 16);
    const char* cA = (const char*)sA;
    const char* cG = (const char*)sBg;
    const char* cU = (const char*)sBu;

#pragma unroll 1
    for (int kk = 0; kk < KHW / 64; ++kk) {
        const int kb = kk * 128;
#pragma unroll
        for (int t = 0; t < 4; ++t) stg16(gA[t] + kb, sA + lb[t]);
#pragma unroll
        for (int t = 0; t < 4; ++t) stg16(gG[t] + kb, sBg + lb[t]);
#pragma unroll
        for (int t = 0; t < 4; ++t) stg16(gU[t] + kb, sBu + lb[t]);
        __syncthreads();
        short8 af[4][2];
#pragma unroll
        for (int i = 0; i < 4; ++i)
#pragma unroll
            for (int ks = 0; ks < 2; ++ks)
                af[i][ks] = *(const short8*)(cA + (wm + i * 16 + l15) * 128 + (c0b ^ (ks << 6)));
        {
            short8 b[4][2];
#pragma unroll
            for (int j = 0; j < 4; ++j)
#pragma unroll
                for (int ks = 0; ks < 2; ++ks)
                    b[j][ks] = *(const short8*)(cG + (wn + j * 16 + l15) * 128 + (c0b ^ (ks << 6)));
#pragma unroll
            for (int i = 0; i < 4; ++i)
#pragma unroll
                for (int j = 0; j < 4; ++j) {
                    accg[i][j] = __builtin_amdgcn_mfma_f32_16x16x32_bf16(af[i][0], b[j][0], accg[i][j], 0, 0, 0);
                    accg[i][j] = __builtin_amdgcn_mfma_f32_16x16x32_bf16(af[i][1], b[j][1], accg[i][j], 0, 0, 0);
                }
        }
        {
            short8 b[4][2];
#pragma unroll
            for (int j = 0; j < 4; ++j)
#pragma unroll
                for (int ks = 0; ks < 2; ++ks)
                    b[j][ks] = *(const short8*)(cU + (wn + j * 16 + l15) * 128 + (c0b ^ (ks << 6)));
#pragma unroll
            for (int i = 0; i < 4; ++i)
#pragma unroll
                for (int j = 0; j < 4; ++j) {
                    accu[i][j] = __builtin_amdgcn_mfma_f32_16x16x32_bf16(af[i][0], b[j][0], accu[i][j], 0, 0, 0);
                    accu[i][j] = __builtin_amdgcn_mfma_f32_16x16x32_bf16(af[i][1], b[j][1], accu[i][j], 0, 0, 0);
                }
        }
        __syncthreads();
    }
}

// ---------------- k_gu: Hbuf = silu(X*Wg^T) * (X*Wu^T), fused, dense tile grid ----------------
__global__ __launch_bounds__(256, 2) void k_gu(
    const unsigned short* __restrict__ X, const unsigned short* __restrict__ Wg,
    const unsigned short* __restrict__ Wu, unsigned short* __restrict__ Hbuf,
    const int* __restrict__ counts, const int* __restrict__ offsets,
    const int* __restrict__ tile_e, const int* __restrict__ tile_m,
    const int* __restrict__ ntiles)
{
    const int t = blockIdx.x;
    if (t >= *ntiles) return;
    const int e = tile_e[t], m0 = tile_m[t];
    const int cnt = counts[e], off = offsets[e];
    const int nt0 = blockIdx.y * 128;

    __shared__ __align__(16) unsigned short sA[128 * 64];
    __shared__ __align__(16) unsigned short sBg[128 * 64];
    __shared__ __align__(16) unsigned short sBu[128 * 64];

    const int tid = threadIdx.x;
    const int wave = tid >> 6, lane = tid & 63;
    const int wm = (wave >> 1) * 64, wn = (wave & 1) * 64;
    const int q = lane >> 4, l15 = lane & 15;

    floatx4 accg[4][4], accu[4][4];
#pragma unroll
    for (int i = 0; i < 4; ++i)
#pragma unroll
        for (int j = 0; j < 4; ++j)
#pragma unroll
            for (int r = 0; r < 4; ++r) { accg[i][j][r] = 0.f; accu[i][j][r] = 0.f; }

    mfma_core2<HID>(X + (size_t)(off + m0) * HID, NPAIR - 1 - (off + m0),
                    Wg + (size_t)e * INTER * HID + (size_t)nt0 * HID,
                    Wu + (size_t)e * INTER * HID + (size_t)nt0 * HID,
                    sA, sBg, sBu, tid, accg, accu);

#pragma unroll
    for (int i = 0; i < 4; ++i)
#pragma unroll
        for (int r = 0; r < 4; ++r) {
            int row = m0 + wm + i * 16 + q * 4 + r;
            if (row < cnt) {
                unsigned short* hrow = Hbuf + (size_t)(off + row) * INTER + nt0;
#pragma unroll
                for (int j = 0; j < 4; ++j) {
                    float g = accg[i][j][r];
                    float s = g / (1.0f + __expf(-g));
                    hrow[wn + j * 16 + l15] = f32_to_bf16_rne(s * accu[i][j][r]);
                }
            }
        }
}

// ---------------- k_d: out[token] += w * (Hbuf * Wd^T), dense tile grid ----------------
__global__ __launch_bounds__(256) void k_d(
    const unsigned short* __restrict__ Hbuf, const unsigned short* __restrict__ Wd,
    float* __restrict__ outf,
    const int* __restrict__ counts, const int* __restrict__ offsets,
    const int* __restrict__ perm_tok, const float* __restrict__ perm_w,
    const int* __restrict__ tile_e, const int* __restrict__ tile_m,
    const int* __restrict__ ntiles)
{
    const int t = blockIdx.x;
    if (t >= *ntiles) return;
    const int e = tile_e[t], m0 = tile_m[t];
    const int cnt = counts[e], off = offsets[e];
    const int nt0 = blockIdx.y * 128;

    __shared__ __align__(16) unsigned short sA[128 * 64];
    __shared__ __align__(16) unsigned short sB[128 * 64];

    const int tid = threadIdx.x;
    const int wave = tid >> 6, lane = tid & 63;
    const int wm = (wave >> 1) * 64, wn = (wave & 1) * 64;
    const int q = lane >> 4, l15 = lane & 15;

    floatx4 acc[4][4];
#pragma unroll
    for (int i = 0; i < 4; ++i)
#pragma unroll
        for (int j = 0; j < 4; ++j)
#pragma unroll
            for (int r = 0; r < 4; ++r) acc[i][j][r] = 0.f;

    mfma_core<INTER>(Hbuf + (size_t)(off + m0) * INTER, NPAIR - 1 - (off + m0),
                     Wd + (size_t)e * HID * INTER + (size_t)nt0 * INTER, sA, sB, tid, acc);

#pragma unroll
    for (int i = 0; i < 4; ++i)
#pragma unroll
        for (int r = 0; r < 4; ++r) {
            int row = m0 + wm + i * 16 + q * 4 + r;
            if (row < cnt) {
                int gpos = off + row;
                int tok = perm_tok[gpos];
                float w = perm_w[gpos];
                float* orow = outf + (size_t)tok * HID + nt0;
#pragma unroll
                for (int j = 0; j < 4; ++j) {
#ifdef __HIP_PLATFORM_AMD__
                    unsafeAtomicAdd(&orow[wn + j * 16 + l15], w * acc[i][j][r]);
#else
                    atomicAdd(&orow[wn + j * 16 + l15], w * acc[i][j][r]);
#endif
                }
            }
        }
}

extern "C" void kernel_launch(void* const* d_in, const int* in_sizes, int n_in,
                              void* d_out, int out_size, void* d_ws, size_t ws_size,
                              hipStream_t stream) {
    const void* tokens = d_in[0];
    const void* eidx   = d_in[1];
    const void* ew     = d_in[2];
    const void* gw     = d_in[3];
    const void* uw     = d_in[4];
    const void* dwp    = d_in[5];
    float* out = (float*)d_out;
    char* ws = (char*)d_ws;

    if (ws_size < WS_NEEDED) {
        hipMemsetAsync(d_out, 0, (size_t)out_size * 4, stream);
        return;
    }

    int*   counts   = (int*)(ws + 0);
    int*   offsets  = (int*)(ws + 64);
    int*   fill     = (int*)(ws + 128);
    int*   flags    = (int*)(ws + 192);
    int*   ntiles   = (int*)(ws + 240);
    int*   tile_e   = (int*)(ws + 256);
    int*   tile_m   = (int*)(ws + 1024);
    int*   perm_tok = (int*)(ws + O_PERMTOK);
    float* perm_w   = (float*)(ws + O_PERMW);
    unsigned short* X  = (unsigned short*)(ws + O_X);
    unsigned short* Wg = (unsigned short*)(ws + O_WG);
    unsigned short* Wu = (unsigned short*)(ws + O_WU);
    unsigned short* Wd = (unsigned short*)(ws + O_WD);
    unsigned short* Hb = (unsigned short*)(ws + O_HB);

    hipMemsetAsync(counts, 0, 256, stream);
    hipMemsetAsync(out, 0, (size_t)out_size * 4, stream);

    k_probe<<<1, 64, 0, stream>>>(tokens, ew, gw, uw, dwp, eidx, flags);
    k_route_count<<<NPAIR / 256, 256, 0, stream>>>((const int*)eidx, counts, flags);
    k_route_scan<<<1, 64, 0, stream>>>(counts, offsets, fill, ntiles, tile_e, tile_m);
    k_route_fill<<<NPAIR / 256, 256, 0, stream>>>((const int*)eidx, ew, offsets, fill,
                                                  perm_tok, perm_w, flags);
    k_gather<<<NPAIR, 256, 0, stream>>>(tokens, perm_tok, X, flags);

    k_transpose64<<<dim3(INTER / 64, HID / 64, NEXP), dim3(32, 8), 0, stream>>>(
        gw, Wg, HID, INTER, flags, 2);
    k_transpose64<<<dim3(INTER / 64, HID / 64, NEXP), dim3(32, 8), 0, stream>>>(
        uw, Wu, HID, INTER, flags, 3);
    k_transpose64<<<dim3(HID / 64, INTER / 64, NEXP), dim3(32, 8), 0, stream>>>(
        dwp, Wd, INTER, HID, flags, 4);

    k_gu<<<dim3(MAXTILE, INTER / 128), 256, 0, stream>>>(X, Wg, Wu, Hb, counts, offsets,
                                                         tile_e, tile_m, ntiles);
    k_d<<<dim3(MAXTILE, HID / 128), 256, 0, stream>>>(Hb, Wd, out, counts, offsets,
                                                      perm_tok, perm_w, tile_e, tile_m, ntiles);
}